// Round 5
// baseline (264.216 us; speedup 1.0000x reference)
//
#include <hip/hip_runtime.h>
#include <hip/hip_bf16.h>
#include <math.h>

#define NB 8192
#define ND 1024
#define KEPS 1e-8f
#define SLOTS 128
#define NTILE 32          // 8192/256 tile grid
#define NWG 528           // NTILE*(NTILE+1)/2 (= 8*66, XCD-bijective)
#define NKT 16            // K-tiles of 64
#define NDBLK (NB / 4)    // dist blocks (4 rows each)

typedef __attribute__((ext_vector_type(8))) __bf16 bf16x8;
typedef __attribute__((ext_vector_type(4))) float f32x4;

// ---------- helpers ----------
__device__ __forceinline__ unsigned int fmono(float f) {
    unsigned int b = __float_as_uint(f);
    return b ^ ((b & 0x80000000u) ? 0xFFFFFFFFu : 0x80000000u);
}
__device__ __forceinline__ unsigned short f2bf(float f) {
    union { float f; unsigned int u; } a;
    a.f = f;
    unsigned int lsb = (a.u >> 16) & 1u;
    a.u += 0x7fffu + lsb;
    return (unsigned short)(a.u >> 16);
}
__device__ __forceinline__ void gload_lds16(const void* g, void* l) {
    __builtin_amdgcn_global_load_lds(
        (const __attribute__((address_space(1))) unsigned int*)g,
        (__attribute__((address_space(3))) unsigned int*)l, 16, 0, 0);
}
__device__ __forceinline__ unsigned long long packmax(float mx, int mc) {
    return ((unsigned long long)fmono(mx) << 32) |
           (unsigned long long)(~(unsigned int)mc);
}

// ---------- kernel 1: row L2-normalize -> bf16 (wave per row); zero dist counter ----------
__global__ __launch_bounds__(256) void normalize_k(const float* __restrict__ x,
                                                   unsigned short* __restrict__ xnb,
                                                   unsigned int* __restrict__ counter) {
    if (blockIdx.x == 0 && threadIdx.x == 0) counter[0] = 0u;
    int row = blockIdx.x * 4 + (threadIdx.x >> 6);
    int l = threadIdx.x & 63;
    const float4* xr = (const float4*)(x + (size_t)row * ND);
    float4 v[4];
    float ss = 0.f;
#pragma unroll
    for (int q = 0; q < 4; ++q) {
        v[q] = xr[q * 64 + l];
        ss += v[q].x * v[q].x + v[q].y * v[q].y + v[q].z * v[q].z + v[q].w * v[q].w;
    }
#pragma unroll
    for (int off = 1; off < 64; off <<= 1) ss += __shfl_xor(ss, off, 64);
    float scale = 1.0f / fmaxf(sqrtf(ss), KEPS);
    ushort4* o = (ushort4*)(xnb + (size_t)row * ND);
#pragma unroll
    for (int q = 0; q < 4; ++q) {
        ushort4 u;
        u.x = f2bf(v[q].x * scale);
        u.y = f2bf(v[q].y * scale);
        u.z = f2bf(v[q].z * scale);
        u.w = f2bf(v[q].w * scale);
        o[q * 64 + l] = u;
    }
}

// ---------- kernel 2: 256^2 2-phase counted-vmcnt bf16 MFMA cos-sim + fused argmax ----------
// LDS per buffer (64KB): A panels [(mq*2+wM)][64r][128B] @0, B @32768.
// Read swizzle: byte-in-row ^= ((row&7)<<4); staging pre-applies the inverse on
// the global source (linear gload_lds dest). Verified bit-exact in R3.
// Schedule (catalog T3 minimum-2-phase): STAGE next tile (8 loads) -> vmcnt(8)
// -> barrier -> [24 ds_read + 64 MFMA, compiler-scheduled] -> barrier.
#define FENCE_BARRIER() do { asm volatile("" ::: "memory"); \
    __builtin_amdgcn_s_barrier(); asm volatile("" ::: "memory"); } while (0)
#define WAIT_VM8() asm volatile("s_waitcnt vmcnt(8)" ::: "memory")
#define WAIT_VM0() asm volatile("s_waitcnt vmcnt(0)" ::: "memory")

// H: 0=A0(@0) 1=A1(@16384) 2=B0(@32768) 3=B1(@49152); DB = buffer byte offset
#define STAGE(H, DB) do { \
    gload_lds16(sp[H][0], ldsb + (DB) + (H) * 16384 + wv * 1024); \
    gload_lds16(sp[H][1], ldsb + (DB) + (H) * 16384 + 8192 + wv * 1024); \
    sp[H][0] += 128; sp[H][1] += 128; } while (0)

#define LOAD_A(CB, MQ) do { \
    const char* Ab_ = ldsb + (CB) + ((MQ) * 2 + wM) * 8192 + rowOff; \
    _Pragma("unroll") for (int mi = 0; mi < 4; ++mi) { \
        af[mi][0] = *(const bf16x8*)(Ab_ + mi * 2048 + ks0); \
        af[mi][1] = *(const bf16x8*)(Ab_ + mi * 2048 + ks1); } } while (0)

#define LOAD_B(CB, BANK, NQ) do { \
    const char* Bb_ = ldsb + (CB) + 32768 + (NQ) * 16384 + wN * 4096 + rowOff; \
    _Pragma("unroll") for (int ni = 0; ni < 2; ++ni) { \
        BANK[ni][0] = *(const bf16x8*)(Bb_ + ni * 2048 + ks0); \
        BANK[ni][1] = *(const bf16x8*)(Bb_ + ni * 2048 + ks1); } } while (0)

#define MFMAQ(MH, NH, BANK) do { \
    _Pragma("unroll") for (int mi = 0; mi < 4; ++mi) \
    _Pragma("unroll") for (int ni = 0; ni < 2; ++ni) { \
        acc[(MH) * 4 + mi][(NH) * 2 + ni] = __builtin_amdgcn_mfma_f32_16x16x32_bf16( \
            af[mi][0], BANK[ni][0], acc[(MH) * 4 + mi][(NH) * 2 + ni], 0, 0, 0); \
        acc[(MH) * 4 + mi][(NH) * 2 + ni] = __builtin_amdgcn_mfma_f32_16x16x32_bf16( \
            af[mi][1], BANK[ni][1], acc[(MH) * 4 + mi][(NH) * 2 + ni], 0, 0, 0); } \
    } while (0)

// one K-tile: stage next tile into DB, confirm current, compute current from CB.
#define KT(CB, DB, PF) do { \
    if (PF) { STAGE(0, DB); STAGE(1, DB); STAGE(2, DB); STAGE(3, DB); WAIT_VM8(); } \
    else { WAIT_VM0(); } \
    FENCE_BARRIER(); \
    bf16x8 af[4][2], b0[2][2], b1[2][2]; \
    LOAD_A(CB, 0); LOAD_B(CB, b0, 0); MFMAQ(0, 0, b0); \
    LOAD_B(CB, b1, 1); MFMAQ(0, 1, b1); \
    LOAD_A(CB, 1); MFMAQ(1, 1, b1); MFMAQ(1, 0, b0); \
    FENCE_BARRIER(); } while (0)

__global__ __launch_bounds__(512, 2) void argmax_gemm(const unsigned short* __restrict__ xnb,
                                                      unsigned long long* __restrict__ partial) {
    extern __shared__ char ldsb[];

    // T1: XCD-bijective swizzle, then triangular decode
    int wg = (int)blockIdx.x;
    int tile = (wg & 7) * (NWG / 8) + (wg >> 3);
    int by = 0, tr = tile;
    while (tr >= NTILE - by) { tr -= NTILE - by; ++by; }
    const int bx = by + tr;  // bx >= by

    const int rowBase = by * 256, colBase = bx * 256;
    const int tid = (int)threadIdx.x;
    const int wv = tid >> 6;   // 0..7
    const int l = tid & 63;
    const int wM = wv >> 2;    // 2 wave-rows x 128
    const int wN = wv & 3;     // 4 wave-cols x 64

    // read-side lane constants (swizzle XOR is lane-constant: row&7 == l&7)
    const int rowOff = (l & 15) * 128;
    const int ks0 = (((l >> 4) * 16)) ^ ((l & 7) << 4);
    const int ks1 = (64 | ((l >> 4) * 16)) ^ ((l & 7) << 4);

    // stage-side: chunk (wv,q) covers region rows (q*8+wv)*8 + (l>>3), 16B col (l&7)
    // source col pre-swizzled: cb = ((l&7) ^ (l>>3)) << 4
    const int scol = (((l & 7) ^ (l >> 3)) << 4);
    const char* xb = (const char*)xnb;
    const char* sp[4][2];
#pragma unroll
    for (int q = 0; q < 2; ++q) {
        int R = (q * 8 + wv) * 8 + (l >> 3);            // 0..127
        int arow = (R >> 6) * 128 + (R & 63);           // + mq*64
        int bcol = (R >> 5) * 64 + (R & 31);            // + nq*32
        sp[0][q] = xb + (size_t)(rowBase + arow) * 2048 + scol;
        sp[1][q] = xb + (size_t)(rowBase + arow + 64) * 2048 + scol;
        sp[2][q] = xb + (size_t)(colBase + bcol) * 2048 + scol;
        sp[3][q] = xb + (size_t)(colBase + bcol + 32) * 2048 + scol;
    }

    // prologue: stage K-tile 0 into buffer 0 ASAP (acc init overlaps latency)
    STAGE(0, 0); STAGE(1, 0); STAGE(2, 0); STAGE(3, 0);

    f32x4 acc[8][4];
#pragma unroll
    for (int m = 0; m < 8; ++m)
#pragma unroll
        for (int n = 0; n < 4; ++n) acc[m][n] = f32x4{0.f, 0.f, 0.f, 0.f};

    // main loop: tile c from buf[c&1]; stage c+1 into buf[(c+1)&1]
    for (int c = 0; c < NKT; c += 2) {
        KT(0, 65536, c + 1 < NKT);
        KT(65536, 0, c + 2 < NKT);
    }

    // ---- epilogue: fused argmax. C/D: col = lane&15, row = (lane>>4)*4 + reg ----
#pragma unroll
    for (int m = 0; m < 8; ++m) {
#pragma unroll
        for (int r = 0; r < 4; ++r) {
            int gi = rowBase + wM * 128 + m * 16 + (l >> 4) * 4 + r;
            float mx = -3.0f;
            int mc = 0x7FFFFFFF;
#pragma unroll
            for (int n = 0; n < 4; ++n) {
                int gj = colBase + wN * 64 + n * 16 + (l & 15);
                float v = (gi == gj) ? -2.0f : acc[m][n][r];
                if (v > mx) { mx = v; mc = gj; }
            }
#pragma unroll
            for (int off = 1; off < 16; off <<= 1) {
                float omx = __shfl_xor(mx, off, 64);
                int omc = __shfl_xor(mc, off, 64);
                if (omx > mx || (omx == mx && omc < mc)) { mx = omx; mc = omc; }
            }
            if ((l & 15) == 0)
                partial[(size_t)gi * SLOTS + (2 * by + (bx - by) * 4 + wN)] = packmax(mx, mc);
        }
    }
    if (bx > by) {
#pragma unroll
        for (int n = 0; n < 4; ++n) {
            int gj = colBase + wN * 64 + n * 16 + (l & 15);
            float mx = -3.0f;
            int mc = 0x7FFFFFFF;
#pragma unroll
            for (int m = 0; m < 8; ++m) {
#pragma unroll
                for (int r = 0; r < 4; ++r) {
                    int gi = rowBase + wM * 128 + m * 16 + (l >> 4) * 4 + r;
                    float v = (gi == gj) ? -2.0f : acc[m][n][r];
                    if (v > mx) { mx = v; mc = gi; }
                }
            }
#pragma unroll
            for (int off = 16; off < 64; off <<= 1) {
                float omx = __shfl_xor(mx, off, 64);
                int omc = __shfl_xor(mc, off, 64);
                if (omx > mx || (omx == mx && omc < mc)) { mx = omx; mc = omc; }
            }
            if ((l >> 4) == 0)
                partial[(size_t)gj * SLOTS + (2 * by + wM)] = packmax(mx, mc);
        }
    }
}

// ---------- kernel 3: slot-reduce -> NN; exact fp32 distance; last block reduces ----------
__global__ __launch_bounds__(256) void dist_k(const float* __restrict__ x,
                                              const unsigned long long* __restrict__ partial,
                                              float* __restrict__ rowloss,
                                              unsigned int* __restrict__ counter,
                                              float* __restrict__ out) {
    int i = blockIdx.x * 4 + (threadIdx.x >> 6);
    int l = threadIdx.x & 63;
    int nv = SLOTS - 2 * (i >> 8);  // valid slots; rest are 0xAA poison (masked)
    unsigned long long p = 0ull;
    if (l < nv) p = partial[(size_t)i * SLOTS + l];
    if (l + 64 < nv) {
        unsigned long long o = partial[(size_t)i * SLOTS + l + 64];
        if (o > p) p = o;
    }
#pragma unroll
    for (int off = 1; off < 64; off <<= 1) {
        unsigned long long o = __shfl_xor(p, off, 64);
        if (o > p) p = o;
    }
    int j = (int)(~(unsigned int)(p & 0xFFFFFFFFull));  // wave-uniform

    const float4* xi = (const float4*)(x + (size_t)i * ND);
    const float4* xj = (const float4*)(x + (size_t)j * ND);
    float4 a[4], b[4];
    float sa = 0.f, sb = 0.f;
#pragma unroll
    for (int q = 0; q < 4; ++q) {
        a[q] = xi[q * 64 + l];
        b[q] = xj[q * 64 + l];
        sa += a[q].x * a[q].x + a[q].y * a[q].y + a[q].z * a[q].z + a[q].w * a[q].w;
        sb += b[q].x * b[q].x + b[q].y * b[q].y + b[q].z * b[q].z + b[q].w * b[q].w;
    }
#pragma unroll
    for (int off = 1; off < 64; off <<= 1) {
        sa += __shfl_xor(sa, off, 64);
        sb += __shfl_xor(sb, off, 64);
    }
    float ia = 1.0f / fmaxf(sqrtf(sa), KEPS);
    float ib = 1.0f / fmaxf(sqrtf(sb), KEPS);
    float ss = 0.f;
#pragma unroll
    for (int q = 0; q < 4; ++q) {
        float dx = a[q].x * ia - b[q].x * ib + KEPS;
        float dy = a[q].y * ia - b[q].y * ib + KEPS;
        float dz = a[q].z * ia - b[q].z * ib + KEPS;
        float dw = a[q].w * ia - b[q].w * ib + KEPS;
        ss += dx * dx + dy * dy + dz * dz + dw * dw;
    }
#pragma unroll
    for (int off = 1; off < 64; off <<= 1) ss += __shfl_xor(ss, off, 64);
    if (l == 0) rowloss[i] = logf(sqrtf(ss) + KEPS);

    // last-block deterministic mean (saves a kernel launch)
    __shared__ int done_s;
    __syncthreads();
    if (threadIdx.x == 0) {
        __threadfence();
        unsigned int old = atomicAdd(counter, 1u);
        done_s = (old == (unsigned int)(NDBLK - 1)) ? 1 : 0;
    }
    __syncthreads();
    if (done_s) {
        __threadfence();
        int t = threadIdx.x;
        float s = 0.f;
#pragma unroll
        for (int k = 0; k < 32; ++k) s += rowloss[t * 32 + k];
#pragma unroll
        for (int off = 1; off < 64; off <<= 1) s += __shfl_xor(s, off, 64);
        __shared__ float fred[4];
        if ((t & 63) == 0) fred[t >> 6] = s;
        __syncthreads();
        if (t == 0)
            out[0] = -(fred[0] + fred[1] + fred[2] + fred[3]) / (float)NB;
    }
}

// ---------- launch ----------
extern "C" void kernel_launch(void* const* d_in, const int* in_sizes, int n_in,
                              void* d_out, int out_size, void* d_ws, size_t ws_size,
                              hipStream_t stream) {
    const float* x = (const float*)d_in[0];
    float* out = (float*)d_out;

    char* ws = (char*)d_ws;
    unsigned short* xnb = (unsigned short*)ws;                        // 16 MB
    unsigned long long* partial =
        (unsigned long long*)(ws + (size_t)NB * ND * 2);              // 8 MB
    float* rowloss = (float*)(ws + (size_t)NB * ND * 2 + (size_t)NB * SLOTS * 8);  // 32 KB
    unsigned int* counter = (unsigned int*)(rowloss + NB);

    (void)hipFuncSetAttribute((const void*)argmax_gemm,
                              hipFuncAttributeMaxDynamicSharedMemorySize, 131072);

    normalize_k<<<NB / 4, 256, 0, stream>>>(x, xnb, counter);
    argmax_gemm<<<NWG, 512, 131072, stream>>>(xnb, partial);
    dist_k<<<NDBLK, 256, 0, stream>>>(x, partial, rowloss, counter, out);
}

// Round 6
// 222.394 us; speedup vs baseline: 1.1881x; 1.1881x over previous
//
#include <hip/hip_runtime.h>
#include <hip/hip_bf16.h>
#include <math.h>

#define NB 8192
#define ND 1024
#define KEPS 1e-8f
#define SLOTS 128
#define NTILE 32          // 8192/256 tile grid
#define NWG 528           // NTILE*(NTILE+1)/2 (= 8*66, XCD-bijective)
#define NKT 16            // K-tiles of 64

typedef __attribute__((ext_vector_type(8))) __bf16 bf16x8;
typedef __attribute__((ext_vector_type(4))) float f32x4;

// ---------- helpers ----------
__device__ __forceinline__ unsigned int fmono(float f) {
    unsigned int b = __float_as_uint(f);
    return b ^ ((b & 0x80000000u) ? 0xFFFFFFFFu : 0x80000000u);
}
__device__ __forceinline__ unsigned short f2bf(float f) {
    union { float f; unsigned int u; } a;
    a.f = f;
    unsigned int lsb = (a.u >> 16) & 1u;
    a.u += 0x7fffu + lsb;
    return (unsigned short)(a.u >> 16);
}
__device__ __forceinline__ void gload_lds16(const void* g, void* l) {
    __builtin_amdgcn_global_load_lds(
        (const __attribute__((address_space(1))) unsigned int*)g,
        (__attribute__((address_space(3))) unsigned int*)l, 16, 0, 0);
}
__device__ __forceinline__ unsigned long long packmax(float mx, int mc) {
    return ((unsigned long long)fmono(mx) << 32) |
           (unsigned long long)(~(unsigned int)mc);
}

// ---------- kernel 1: row L2-normalize -> bf16 (wave per row) ----------
__global__ __launch_bounds__(256) void normalize_k(const float* __restrict__ x,
                                                   unsigned short* __restrict__ xnb) {
    int row = blockIdx.x * 4 + (threadIdx.x >> 6);
    int l = threadIdx.x & 63;
    const float4* xr = (const float4*)(x + (size_t)row * ND);
    float4 v[4];
    float ss = 0.f;
#pragma unroll
    for (int q = 0; q < 4; ++q) {
        v[q] = xr[q * 64 + l];
        ss += v[q].x * v[q].x + v[q].y * v[q].y + v[q].z * v[q].z + v[q].w * v[q].w;
    }
#pragma unroll
    for (int off = 1; off < 64; off <<= 1) ss += __shfl_xor(ss, off, 64);
    float scale = 1.0f / fmaxf(sqrtf(ss), KEPS);
    ushort4* o = (ushort4*)(xnb + (size_t)row * ND);
#pragma unroll
    for (int q = 0; q < 4; ++q) {
        ushort4 u;
        u.x = f2bf(v[q].x * scale);
        u.y = f2bf(v[q].y * scale);
        u.z = f2bf(v[q].z * scale);
        u.w = f2bf(v[q].w * scale);
        o[q * 64 + l] = u;
    }
}

// ---------- kernel 2: 256^2 m201-style 4-phase bf16 MFMA cos-sim + fused argmax ----------
// LDS per buffer (64KB): A panels [(mq*2+wM)][64r][128B] @0, B @32768.
// Read swizzle: byte-in-row ^= ((row&7)<<4); staging pre-applies the inverse on
// the global source (linear gload_lds dest). Bit-exact since R2.
// Per phase: {ds_read frags, 1 half-tile gload_lds} -> s_barrier -> setprio(1)
// 16 MFMA setprio(0) -> s_barrier. NO lgkmcnt/sched_barrier pins (m141 lesson):
// compiler inserts progressive lgkmcnt between ds_read and MFMA.
// vmcnt(6) once per tile boundary (3 half-tiles in flight), vmcnt(0) at tile 14.
#define FENCE_BARRIER() do { asm volatile("" ::: "memory"); \
    __builtin_amdgcn_s_barrier(); asm volatile("" ::: "memory"); } while (0)
#define WAIT_VM6() asm volatile("s_waitcnt vmcnt(6)" ::: "memory")
#define WAIT_VM0() asm volatile("s_waitcnt vmcnt(0)" ::: "memory")

// H: 0=A0(@0) 1=A1(@16384) 2=B0(@32768) 3=B1(@49152); DB = buffer byte offset
#define STAGE(H, DB) do { \
    gload_lds16(sp[H][0], ldsb + (DB) + (H) * 16384 + wv * 1024); \
    gload_lds16(sp[H][1], ldsb + (DB) + (H) * 16384 + 8192 + wv * 1024); \
    sp[H][0] += 128; sp[H][1] += 128; } while (0)

#define LOAD_A(CB, MQ) do { \
    const char* Ab_ = ldsb + (CB) + ((MQ) * 2 + wM) * 8192 + rowOff; \
    _Pragma("unroll") for (int mi = 0; mi < 4; ++mi) { \
        af[mi][0] = *(const bf16x8*)(Ab_ + mi * 2048 + ks0); \
        af[mi][1] = *(const bf16x8*)(Ab_ + mi * 2048 + ks1); } } while (0)

#define LOAD_B(CB, BANK, NQ) do { \
    const char* Bb_ = ldsb + (CB) + 32768 + (NQ) * 16384 + wN * 4096 + rowOff; \
    _Pragma("unroll") for (int ni = 0; ni < 2; ++ni) { \
        BANK[ni][0] = *(const bf16x8*)(Bb_ + ni * 2048 + ks0); \
        BANK[ni][1] = *(const bf16x8*)(Bb_ + ni * 2048 + ks1); } } while (0)

#define MFMAQ(MH, NH, BANK) do { \
    __builtin_amdgcn_s_setprio(1); \
    _Pragma("unroll") for (int mi = 0; mi < 4; ++mi) \
    _Pragma("unroll") for (int ni = 0; ni < 2; ++ni) { \
        acc[(MH) * 4 + mi][(NH) * 2 + ni] = __builtin_amdgcn_mfma_f32_16x16x32_bf16( \
            af[mi][0], BANK[ni][0], acc[(MH) * 4 + mi][(NH) * 2 + ni], 0, 0, 0); \
        acc[(MH) * 4 + mi][(NH) * 2 + ni] = __builtin_amdgcn_mfma_f32_16x16x32_bf16( \
            af[mi][1], BANK[ni][1], acc[(MH) * 4 + mi][(NH) * 2 + ni], 0, 0, 0); } \
    __builtin_amdgcn_s_setprio(0); } while (0)

// one K-tile c (compute from CB): p0 stages (c+1).A1 into DB; p1-p3 stage
// (c+2).{A0,B0,B1} into CB regions freed at p0/p0/p1 respectively.
#define KTILE(CB, DB, S1, S2, FINAL) do { \
    bf16x8 af[4][2], b0[2][2], b1[2][2]; \
    LOAD_A(CB, 0); LOAD_B(CB, b0, 0); \
    if (S1) STAGE(1, DB); \
    FENCE_BARRIER(); MFMAQ(0, 0, b0); FENCE_BARRIER(); \
    LOAD_B(CB, b1, 1); \
    if (S2) STAGE(0, CB); \
    FENCE_BARRIER(); MFMAQ(0, 1, b1); FENCE_BARRIER(); \
    LOAD_A(CB, 1); \
    if (S2) STAGE(2, CB); \
    FENCE_BARRIER(); MFMAQ(1, 1, b1); FENCE_BARRIER(); \
    if (S2) STAGE(3, CB); \
    MFMAQ(1, 0, b0); \
    if (FINAL) { WAIT_VM0(); } else { WAIT_VM6(); } \
    FENCE_BARRIER(); } while (0)

#define KTILE_LAST(CB) do { \
    bf16x8 af[4][2], b0[2][2], b1[2][2]; \
    LOAD_A(CB, 0); LOAD_B(CB, b0, 0); \
    FENCE_BARRIER(); MFMAQ(0, 0, b0); FENCE_BARRIER(); \
    LOAD_B(CB, b1, 1); \
    FENCE_BARRIER(); MFMAQ(0, 1, b1); FENCE_BARRIER(); \
    LOAD_A(CB, 1); \
    FENCE_BARRIER(); MFMAQ(1, 1, b1); FENCE_BARRIER(); \
    MFMAQ(1, 0, b0); } while (0)

__global__ __launch_bounds__(512, 2) void argmax_gemm(const unsigned short* __restrict__ xnb,
                                                      unsigned long long* __restrict__ partial) {
    extern __shared__ char ldsb[];

    // T1: XCD-bijective swizzle, then triangular decode
    int wg = (int)blockIdx.x;
    int tile = (wg & 7) * (NWG / 8) + (wg >> 3);
    int by = 0, tr = tile;
    while (tr >= NTILE - by) { tr -= NTILE - by; ++by; }
    const int bx = by + tr;  // bx >= by

    const int rowBase = by * 256, colBase = bx * 256;
    const int tid = (int)threadIdx.x;
    const int wv = tid >> 6;   // 0..7
    const int l = tid & 63;
    const int wM = wv >> 2;    // 2 wave-rows x 128
    const int wN = wv & 3;     // 4 wave-cols x 64

    // read-side lane constants (swizzle XOR is lane-constant: row&7 == l&7)
    const int rowOff = (l & 15) * 128;
    const int ks0 = (((l >> 4) * 16)) ^ ((l & 7) << 4);
    const int ks1 = (64 | ((l >> 4) * 16)) ^ ((l & 7) << 4);

    // stage-side: chunk (wv,q) covers region rows (q*8+wv)*8 + (l>>3), 16B col (l&7)
    // source col pre-swizzled: cb = ((l&7) ^ (l>>3)) << 4
    const int scol = (((l & 7) ^ (l >> 3)) << 4);
    const char* xb = (const char*)xnb;
    const char* sp[4][2];
#pragma unroll
    for (int q = 0; q < 2; ++q) {
        int R = (q * 8 + wv) * 8 + (l >> 3);            // 0..127
        int arow = (R >> 6) * 128 + (R & 63);           // + mq*64
        int bcol = (R >> 5) * 64 + (R & 31);            // + nq*32
        sp[0][q] = xb + (size_t)(rowBase + arow) * 2048 + scol;
        sp[1][q] = xb + (size_t)(rowBase + arow + 64) * 2048 + scol;
        sp[2][q] = xb + (size_t)(colBase + bcol) * 2048 + scol;
        sp[3][q] = xb + (size_t)(colBase + bcol + 32) * 2048 + scol;
    }

    // prologue: tile0 fully + tile1 {A0,B0,B1}; wait tile0 (6 loads remain flying)
    STAGE(0, 0); STAGE(2, 0); STAGE(3, 0); STAGE(1, 0);
    STAGE(0, 65536); STAGE(2, 65536); STAGE(3, 65536);

    f32x4 acc[8][4];
#pragma unroll
    for (int m = 0; m < 8; ++m)
#pragma unroll
        for (int n = 0; n < 4; ++n) acc[m][n] = f32x4{0.f, 0.f, 0.f, 0.f};

    WAIT_VM6();
    FENCE_BARRIER();

    // main: tiles 0..13 full pipeline; 14 drains; 15 compute-only
    for (int c = 0; c < 12; c += 2) {
        KTILE(0, 65536, true, true, false);
        KTILE(65536, 0, true, true, false);
    }
    KTILE(0, 65536, true, true, false);        // tile 12
    KTILE(65536, 0, true, true, false);        // tile 13
    KTILE(0, 65536, true, false, true);        // tile 14: stage t15.A1 only; drain
    KTILE_LAST(65536);                         // tile 15

    // ---- epilogue: fused argmax. C/D: col = lane&15, row = (lane>>4)*4 + reg ----
#pragma unroll
    for (int m = 0; m < 8; ++m) {
#pragma unroll
        for (int r = 0; r < 4; ++r) {
            int gi = rowBase + wM * 128 + m * 16 + (l >> 4) * 4 + r;
            float mx = -3.0f;
            int mc = 0x7FFFFFFF;
#pragma unroll
            for (int n = 0; n < 4; ++n) {
                int gj = colBase + wN * 64 + n * 16 + (l & 15);
                float v = (gi == gj) ? -2.0f : acc[m][n][r];
                if (v > mx) { mx = v; mc = gj; }
            }
#pragma unroll
            for (int off = 1; off < 16; off <<= 1) {
                float omx = __shfl_xor(mx, off, 64);
                int omc = __shfl_xor(mc, off, 64);
                if (omx > mx || (omx == mx && omc < mc)) { mx = omx; mc = omc; }
            }
            if ((l & 15) == 0)
                partial[(size_t)gi * SLOTS + (2 * by + (bx - by) * 4 + wN)] = packmax(mx, mc);
        }
    }
    if (bx > by) {
#pragma unroll
        for (int n = 0; n < 4; ++n) {
            int gj = colBase + wN * 64 + n * 16 + (l & 15);
            float mx = -3.0f;
            int mc = 0x7FFFFFFF;
#pragma unroll
            for (int m = 0; m < 8; ++m) {
#pragma unroll
                for (int r = 0; r < 4; ++r) {
                    int gi = rowBase + wM * 128 + m * 16 + (l >> 4) * 4 + r;
                    float v = (gi == gj) ? -2.0f : acc[m][n][r];
                    if (v > mx) { mx = v; mc = gi; }
                }
            }
#pragma unroll
            for (int off = 16; off < 64; off <<= 1) {
                float omx = __shfl_xor(mx, off, 64);
                int omc = __shfl_xor(mc, off, 64);
                if (omx > mx || (omx == mx && omc < mc)) { mx = omx; mc = omc; }
            }
            if ((l >> 4) == 0)
                partial[(size_t)gj * SLOTS + (2 * by + wM)] = packmax(mx, mc);
        }
    }
}

// ---------- kernel 3: slot-reduce -> NN idx; exact fp32 distance + loss (wave/row) ----------
__global__ __launch_bounds__(256) void dist_k(const float* __restrict__ x,
                                              const unsigned long long* __restrict__ partial,
                                              float* __restrict__ rowloss) {
    int i = blockIdx.x * 4 + (threadIdx.x >> 6);
    int l = threadIdx.x & 63;
    int nv = SLOTS - 2 * (i >> 8);  // valid slots; rest are 0xAA poison (masked)
    unsigned long long p = 0ull;
    if (l < nv) p = partial[(size_t)i * SLOTS + l];
    if (l + 64 < nv) {
        unsigned long long o = partial[(size_t)i * SLOTS + l + 64];
        if (o > p) p = o;
    }
#pragma unroll
    for (int off = 1; off < 64; off <<= 1) {
        unsigned long long o = __shfl_xor(p, off, 64);
        if (o > p) p = o;
    }
    int j = (int)(~(unsigned int)(p & 0xFFFFFFFFull));  // wave-uniform

    const float4* xi = (const float4*)(x + (size_t)i * ND);
    const float4* xj = (const float4*)(x + (size_t)j * ND);
    float4 a[4], b[4];
    float sa = 0.f, sb = 0.f;
#pragma unroll
    for (int q = 0; q < 4; ++q) {
        a[q] = xi[q * 64 + l];
        b[q] = xj[q * 64 + l];
        sa += a[q].x * a[q].x + a[q].y * a[q].y + a[q].z * a[q].z + a[q].w * a[q].w;
        sb += b[q].x * b[q].x + b[q].y * b[q].y + b[q].z * b[q].z + b[q].w * b[q].w;
    }
#pragma unroll
    for (int off = 1; off < 64; off <<= 1) {
        sa += __shfl_xor(sa, off, 64);
        sb += __shfl_xor(sb, off, 64);
    }
    float ia = 1.0f / fmaxf(sqrtf(sa), KEPS);
    float ib = 1.0f / fmaxf(sqrtf(sb), KEPS);
    float ss = 0.f;
#pragma unroll
    for (int q = 0; q < 4; ++q) {
        float dx = a[q].x * ia - b[q].x * ib + KEPS;
        float dy = a[q].y * ia - b[q].y * ib + KEPS;
        float dz = a[q].z * ia - b[q].z * ib + KEPS;
        float dw = a[q].w * ia - b[q].w * ib + KEPS;
        ss += dx * dx + dy * dy + dz * dz + dw * dw;
    }
#pragma unroll
    for (int off = 1; off < 64; off <<= 1) ss += __shfl_xor(ss, off, 64);
    if (l == 0) rowloss[i] = -logf(sqrtf(ss) + KEPS);
}

// ---------- kernel 4: mean over rows ----------
__global__ __launch_bounds__(1024) void reduce_k(const float* __restrict__ rowloss,
                                                 float* __restrict__ out) {
    int t = threadIdx.x;
    float s = 0.0f;
#pragma unroll
    for (int k = 0; k < 8; ++k) s += rowloss[t + k * 1024];
#pragma unroll
    for (int off = 32; off > 0; off >>= 1) s += __shfl_down(s, off, 64);
    __shared__ float sred[16];
    if ((t & 63) == 0) sred[t >> 6] = s;
    __syncthreads();
    if (t == 0) {
        float tot = 0.0f;
        for (int k = 0; k < 16; ++k) tot += sred[k];
        out[0] = tot / (float)NB;
    }
}

// ---------- launch ----------
extern "C" void kernel_launch(void* const* d_in, const int* in_sizes, int n_in,
                              void* d_out, int out_size, void* d_ws, size_t ws_size,
                              hipStream_t stream) {
    const float* x = (const float*)d_in[0];
    float* out = (float*)d_out;

    char* ws = (char*)d_ws;
    unsigned short* xnb = (unsigned short*)ws;                        // 16 MB
    unsigned long long* partial =
        (unsigned long long*)(ws + (size_t)NB * ND * 2);              // 8 MB
    float* rowloss = (float*)(ws + (size_t)NB * ND * 2 + (size_t)NB * SLOTS * 8);  // 32 KB

    (void)hipFuncSetAttribute((const void*)argmax_gemm,
                              hipFuncAttributeMaxDynamicSharedMemorySize, 131072);

    normalize_k<<<NB / 4, 256, 0, stream>>>(x, xnb);
    argmax_gemm<<<NWG, 512, 131072, stream>>>(xnb, partial);
    dist_k<<<NB / 4, 256, 0, stream>>>(x, partial, rowloss);
    reduce_k<<<1, 1024, 0, stream>>>(rowloss, out);
}

// Round 7
// 184.697 us; speedup vs baseline: 1.4305x; 1.2041x over previous
//
#include <hip/hip_runtime.h>
#include <hip/hip_bf16.h>
#include <math.h>

#define NB 8192
#define ND 1024
#define KEPS 1e-8f
#define SLOTS 128
#define NTIL 64           // 8192/128 tile grid
#define NWG 2080          // NTIL*(NTIL+1)/2 (= 8*260, XCD-bijective)
#define NKT 32            // K-tiles of 32

typedef __attribute__((ext_vector_type(8))) __bf16 bf16x8;
typedef __attribute__((ext_vector_type(4))) float f32x4;

// ---------- helpers ----------
__device__ __forceinline__ unsigned int fmono(float f) {
    unsigned int b = __float_as_uint(f);
    return b ^ ((b & 0x80000000u) ? 0xFFFFFFFFu : 0x80000000u);
}
__device__ __forceinline__ unsigned short f2bf(float f) {
    union { float f; unsigned int u; } a;
    a.f = f;
    unsigned int lsb = (a.u >> 16) & 1u;
    a.u += 0x7fffu + lsb;
    return (unsigned short)(a.u >> 16);
}
__device__ __forceinline__ void gload_lds16(const void* g, void* l) {
    __builtin_amdgcn_global_load_lds(
        (const __attribute__((address_space(1))) unsigned int*)g,
        (__attribute__((address_space(3))) unsigned int*)l, 16, 0, 0);
}
__device__ __forceinline__ unsigned long long packmax(float mx, int mc) {
    return ((unsigned long long)fmono(mx) << 32) |
           (unsigned long long)(~(unsigned int)mc);
}

// ---------- kernel 1: row L2-normalize -> bf16 (wave per row) ----------
__global__ __launch_bounds__(256) void normalize_k(const float* __restrict__ x,
                                                   unsigned short* __restrict__ xnb) {
    int row = blockIdx.x * 4 + (threadIdx.x >> 6);
    int l = threadIdx.x & 63;
    const float4* xr = (const float4*)(x + (size_t)row * ND);
    float4 v[4];
    float ss = 0.f;
#pragma unroll
    for (int q = 0; q < 4; ++q) {
        v[q] = xr[q * 64 + l];
        ss += v[q].x * v[q].x + v[q].y * v[q].y + v[q].z * v[q].z + v[q].w * v[q].w;
    }
#pragma unroll
    for (int off = 1; off < 64; off <<= 1) ss += __shfl_xor(ss, off, 64);
    float scale = 1.0f / fmaxf(sqrtf(ss), KEPS);
    ushort4* o = (ushort4*)(xnb + (size_t)row * ND);
#pragma unroll
    for (int q = 0; q < 4; ++q) {
        ushort4 u;
        u.x = f2bf(v[q].x * scale);
        u.y = f2bf(v[q].y * scale);
        u.z = f2bf(v[q].z * scale);
        u.w = f2bf(v[q].w * scale);
        o[q * 64 + l] = u;
    }
}

// ---------- kernel 2: 128^2 counted-vmcnt dbuf bf16 MFMA cos-sim + fused argmax ----------
// 4 waves (2M x 2N), per-wave 64x64 (acc[4][4] = 64 regs -> 4 blocks/CU).
// LDS per buffer (16KB): A rows 0..127 @0 (64B rows), B cols 0..127 @8192.
// Read swizzle: 16B slot ^= ((row>>1)&3)<<4 (2 lanes/bank on b128 reads);
// staging pre-applies the inverse on the global source (linear gload_lds dest).
// Pipeline (R4-verified): STAGE next tile (4 loads/wave) -> vmcnt(4) -> barrier
// -> compute (8 ds_read_b128 + 16 MFMA, compiler-scheduled) -> barrier.
#define FENCE_BARRIER() do { asm volatile("" ::: "memory"); \
    __builtin_amdgcn_s_barrier(); asm volatile("" ::: "memory"); } while (0)
#define WAIT_VM4() asm volatile("s_waitcnt vmcnt(4)" ::: "memory")
#define WAIT_VM0() asm volatile("s_waitcnt vmcnt(0)" ::: "memory")

// stage one K-tile into buffer at byte DB; 4 chunks/wave (A q0,q1; B q0,q1)
#define STAGEALL(DB) do { \
    gload_lds16(spA0, ldsb + (DB) + (wv * 2 + 0) * 1024); \
    gload_lds16(spA1, ldsb + (DB) + (wv * 2 + 1) * 1024); \
    gload_lds16(spB0, ldsb + (DB) + 8192 + (wv * 2 + 0) * 1024); \
    gload_lds16(spB1, ldsb + (DB) + 8192 + (wv * 2 + 1) * 1024); \
    spA0 += 64; spA1 += 64; spB0 += 64; spB1 += 64; } while (0)

#define KT(CB, DB, PF) do { \
    if (PF) { STAGEALL(DB); WAIT_VM4(); } else { WAIT_VM0(); } \
    FENCE_BARRIER(); \
    bf16x8 af[4], bf[4]; \
    _Pragma("unroll") for (int mi = 0; mi < 4; ++mi) \
        af[mi] = *(const bf16x8*)(ldsb + (CB) + wM * 4096 + mi * 1024 + rowks); \
    _Pragma("unroll") for (int ni = 0; ni < 4; ++ni) \
        bf[ni] = *(const bf16x8*)(ldsb + (CB) + 8192 + wN * 4096 + ni * 1024 + rowks); \
    _Pragma("unroll") for (int mi = 0; mi < 4; ++mi) \
    _Pragma("unroll") for (int ni = 0; ni < 4; ++ni) \
        acc[mi][ni] = __builtin_amdgcn_mfma_f32_16x16x32_bf16(af[mi], bf[ni], acc[mi][ni], 0, 0, 0); \
    FENCE_BARRIER(); } while (0)

__global__ __launch_bounds__(256, 4) void argmax_gemm(const unsigned short* __restrict__ xnb,
                                                      unsigned long long* __restrict__ partial) {
    __shared__ char ldsb[32768];

    // T1: XCD-bijective swizzle (2080 = 8*260), then triangular decode
    int wg = (int)blockIdx.x;
    int tile = (wg & 7) * (NWG / 8) + (wg >> 3);
    int by = 0, tr = tile;
    while (tr >= NTIL - by) { tr -= NTIL - by; ++by; }
    const int bx = by + tr;  // bx >= by

    const int rowBase = by * 128, colBase = bx * 128;
    const int tid = (int)threadIdx.x;
    const int wv = tid >> 6;   // 0..3
    const int l = tid & 63;
    const int wM = wv >> 1;    // 2 wave-rows x 64
    const int wN = wv & 1;     // 2 wave-cols x 64

    // read-side: lane l reads row (l&15) of a 16-row block, 16B slot (l>>4)
    // physical slot = logical ^ ((row>>1)&3); row&7 == l&7 within each block
    const int rowks = (l & 15) * 64 + (((l >> 4) * 16) ^ (((l >> 1) & 3) << 4));

    // stage-side: lane covers chunk-row l>>2, physical slot l&3;
    // source slot = (l&3) ^ ((l>>3)&3)  (inverse of the read swizzle)
    const int scol = (((l & 3) ^ ((l >> 3) & 3)) << 4);
    const char* xb = (const char*)xnb;
    // chunk (wv,q) covers region rows (wv*2+q)*16 + (l>>2); A rows / B cols linear
    const int r0 = (wv * 2 + 0) * 16 + (l >> 2);
    const int r1 = (wv * 2 + 1) * 16 + (l >> 2);
    const char* spA0 = xb + (size_t)(rowBase + r0) * 2048 + scol;
    const char* spA1 = xb + (size_t)(rowBase + r1) * 2048 + scol;
    const char* spB0 = xb + (size_t)(colBase + r0) * 2048 + scol;
    const char* spB1 = xb + (size_t)(colBase + r1) * 2048 + scol;

    f32x4 acc[4][4];
#pragma unroll
    for (int m = 0; m < 4; ++m)
#pragma unroll
        for (int n = 0; n < 4; ++n) acc[m][n] = f32x4{0.f, 0.f, 0.f, 0.f};

    // prologue: stage tile 0 into buf0
    STAGEALL(0);

    // main loop: tile c from buf[c&1]; stage c+1 into buf[(c+1)&1]; vmcnt(4)
    for (int c = 0; c < NKT; c += 2) {
        KT(0, 16384, c + 1 < NKT);
        KT(16384, 0, c + 2 < NKT);
    }

    // ---- epilogue: fused argmax. C/D: col = lane&15, row = (lane>>4)*4 + reg ----
    // row path: rows of by-block; slot = (bx-by)*2 + wN  in [0, (64-by)*2)
#pragma unroll
    for (int mi = 0; mi < 4; ++mi) {
#pragma unroll
        for (int r = 0; r < 4; ++r) {
            int gi = rowBase + wM * 64 + mi * 16 + (l >> 4) * 4 + r;
            float mx = -3.0f;
            int mc = 0x7FFFFFFF;
#pragma unroll
            for (int ni = 0; ni < 4; ++ni) {
                int gj = colBase + wN * 64 + ni * 16 + (l & 15);
                float v = (gi == gj) ? -2.0f : acc[mi][ni][r];
                if (v > mx) { mx = v; mc = gj; }
            }
#pragma unroll
            for (int off = 1; off < 16; off <<= 1) {
                float omx = __shfl_xor(mx, off, 64);
                int omc = __shfl_xor(mc, off, 64);
                if (omx > mx || (omx == mx && omc < mc)) { mx = omx; mc = omc; }
            }
            if ((l & 15) == 0)
                partial[(size_t)gi * SLOTS + (bx - by) * 2 + wN] = packmax(mx, mc);
        }
    }
    // col path (transpose view, bx > by): rows of bx-block; slot = (64-bx)*2 + by*2 + wM
    if (bx > by) {
#pragma unroll
        for (int ni = 0; ni < 4; ++ni) {
            int gj = colBase + wN * 64 + ni * 16 + (l & 15);
            float mx = -3.0f;
            int mc = 0x7FFFFFFF;
#pragma unroll
            for (int mi = 0; mi < 4; ++mi) {
#pragma unroll
                for (int r = 0; r < 4; ++r) {
                    int gi = rowBase + wM * 64 + mi * 16 + (l >> 4) * 4 + r;
                    float v = (gi == gj) ? -2.0f : acc[mi][ni][r];
                    if (v > mx) { mx = v; mc = gi; }   // ascending gi, strict >
                }
            }
#pragma unroll
            for (int off = 16; off < 64; off <<= 1) {
                float omx = __shfl_xor(mx, off, 64);
                int omc = __shfl_xor(mc, off, 64);
                if (omx > mx || (omx == mx && omc < mc)) { mx = omx; mc = omc; }
            }
            if ((l >> 4) == 0)
                partial[(size_t)gj * SLOTS + (NTIL - bx) * 2 + by * 2 + wM] = packmax(mx, mc);
        }
    }
}

// ---------- kernel 3: slot-reduce -> NN idx; exact fp32 distance + loss (wave/row) ----------
__global__ __launch_bounds__(256) void dist_k(const float* __restrict__ x,
                                              const unsigned long long* __restrict__ partial,
                                              float* __restrict__ rowloss) {
    int i = blockIdx.x * 4 + (threadIdx.x >> 6);
    int l = threadIdx.x & 63;
    // all 128 slots are written for every row (exact partition)
    unsigned long long p = partial[(size_t)i * SLOTS + l];
    {
        unsigned long long o = partial[(size_t)i * SLOTS + l + 64];
        if (o > p) p = o;
    }
#pragma unroll
    for (int off = 1; off < 64; off <<= 1) {
        unsigned long long o = __shfl_xor(p, off, 64);
        if (o > p) p = o;
    }
    int j = (int)(~(unsigned int)(p & 0xFFFFFFFFull));  // wave-uniform

    const float4* xi = (const float4*)(x + (size_t)i * ND);
    const float4* xj = (const float4*)(x + (size_t)j * ND);
    float4 a[4], b[4];
    float sa = 0.f, sb = 0.f;
#pragma unroll
    for (int q = 0; q < 4; ++q) {
        a[q] = xi[q * 64 + l];
        b[q] = xj[q * 64 + l];
        sa += a[q].x * a[q].x + a[q].y * a[q].y + a[q].z * a[q].z + a[q].w * a[q].w;
        sb += b[q].x * b[q].x + b[q].y * b[q].y + b[q].z * b[q].z + b[q].w * b[q].w;
    }
#pragma unroll
    for (int off = 1; off < 64; off <<= 1) {
        sa += __shfl_xor(sa, off, 64);
        sb += __shfl_xor(sb, off, 64);
    }
    float ia = 1.0f / fmaxf(sqrtf(sa), KEPS);
    float ib = 1.0f / fmaxf(sqrtf(sb), KEPS);
    float ss = 0.f;
#pragma unroll
    for (int q = 0; q < 4; ++q) {
        float dx = a[q].x * ia - b[q].x * ib + KEPS;
        float dy = a[q].y * ia - b[q].y * ib + KEPS;
        float dz = a[q].z * ia - b[q].z * ib + KEPS;
        float dw = a[q].w * ia - b[q].w * ib + KEPS;
        ss += dx * dx + dy * dy + dz * dz + dw * dw;
    }
#pragma unroll
    for (int off = 1; off < 64; off <<= 1) ss += __shfl_xor(ss, off, 64);
    if (l == 0) rowloss[i] = -logf(sqrtf(ss) + KEPS);
}

// ---------- kernel 4: mean over rows ----------
__global__ __launch_bounds__(1024) void reduce_k(const float* __restrict__ rowloss,
                                                 float* __restrict__ out) {
    int t = threadIdx.x;
    float s = 0.0f;
#pragma unroll
    for (int k = 0; k < 8; ++k) s += rowloss[t + k * 1024];
#pragma unroll
    for (int off = 32; off > 0; off >>= 1) s += __shfl_down(s, off, 64);
    __shared__ float sred[16];
    if ((t & 63) == 0) sred[t >> 6] = s;
    __syncthreads();
    if (t == 0) {
        float tot = 0.0f;
        for (int k = 0; k < 16; ++k) tot += sred[k];
        out[0] = tot / (float)NB;
    }
}

// ---------- launch ----------
extern "C" void kernel_launch(void* const* d_in, const int* in_sizes, int n_in,
                              void* d_out, int out_size, void* d_ws, size_t ws_size,
                              hipStream_t stream) {
    const float* x = (const float*)d_in[0];
    float* out = (float*)d_out;

    char* ws = (char*)d_ws;
    unsigned short* xnb = (unsigned short*)ws;                        // 16 MB
    unsigned long long* partial =
        (unsigned long long*)(ws + (size_t)NB * ND * 2);              // 8 MB
    float* rowloss = (float*)(ws + (size_t)NB * ND * 2 + (size_t)NB * SLOTS * 8);  // 32 KB

    normalize_k<<<NB / 4, 256, 0, stream>>>(x, xnb);
    argmax_gemm<<<NWG, 256, 0, stream>>>(xnb, partial);
    dist_k<<<NB / 4, 256, 0, stream>>>(x, partial, rowloss);
    reduce_k<<<1, 1024, 0, stream>>>(rowloss, out);
}

// Round 11
// 183.193 us; speedup vs baseline: 1.4423x; 1.0082x over previous
//
#include <hip/hip_runtime.h>
#include <hip/hip_bf16.h>
#include <math.h>

#define NB 8192
#define ND 1024
#define KEPS 1e-8f
#define SLOTS 128
#define NTIL 64           // 8192/128 tile grid
#define NWG 2080          // NTIL*(NTIL+1)/2 (= 8*260, XCD-bijective)
#define NKT 32            // K-tiles of 32

typedef __attribute__((ext_vector_type(8))) __bf16 bf16x8;
typedef __attribute__((ext_vector_type(4))) float f32x4;

// ---------- helpers ----------
__device__ __forceinline__ unsigned int fmono(float f) {
    unsigned int b = __float_as_uint(f);
    return b ^ ((b & 0x80000000u) ? 0xFFFFFFFFu : 0x80000000u);
}
__device__ __forceinline__ unsigned short f2bf(float f) {
    union { float f; unsigned int u; } a;
    a.f = f;
    unsigned int lsb = (a.u >> 16) & 1u;
    a.u += 0x7fffu + lsb;
    return (unsigned short)(a.u >> 16);
}
__device__ __forceinline__ void gload_lds16(const void* g, void* l) {
    __builtin_amdgcn_global_load_lds(
        (const __attribute__((address_space(1))) unsigned int*)g,
        (__attribute__((address_space(3))) unsigned int*)l, 16, 0, 0);
}
__device__ __forceinline__ unsigned long long packmax(float mx, int mc) {
    return ((unsigned long long)fmono(mx) << 32) |
           (unsigned long long)(~(unsigned int)mc);
}

// ---------- kernel 1: row L2-normalize -> bf16 (wave per row) ----------
__global__ __launch_bounds__(256) void normalize_k(const float* __restrict__ x,
                                                   unsigned short* __restrict__ xnb) {
    int row = blockIdx.x * 4 + (threadIdx.x >> 6);
    int l = threadIdx.x & 63;
    const float4* xr = (const float4*)(x + (size_t)row * ND);
    float4 v[4];
    float ss = 0.f;
#pragma unroll
    for (int q = 0; q < 4; ++q) {
        v[q] = xr[q * 64 + l];
        ss += v[q].x * v[q].x + v[q].y * v[q].y + v[q].z * v[q].z + v[q].w * v[q].w;
    }
#pragma unroll
    for (int off = 1; off < 64; off <<= 1) ss += __shfl_xor(ss, off, 64);
    float scale = 1.0f / fmaxf(sqrtf(ss), KEPS);
    ushort4* o = (ushort4*)(xnb + (size_t)row * ND);
#pragma unroll
    for (int q = 0; q < 4; ++q) {
        ushort4 u;
        u.x = f2bf(v[q].x * scale);
        u.y = f2bf(v[q].y * scale);
        u.z = f2bf(v[q].z * scale);
        u.w = f2bf(v[q].w * scale);
        o[q * 64 + l] = u;
    }
}

// ---------- kernel 2: 128^2 3-deep pipeline bf16 MFMA cos-sim + fused argmax ----------
// 4 waves (2M x 2N), per-wave 64x64, acc[4][4]; 3 x 16KB LDS buffers -> 48KB,
// 3 blocks/CU. Per tile: vmcnt(4) -> barrier -> STAGE(c+2) -> compute(c).
// Single barrier/tile is race-free: barrier at tile c proves all waves done
// reading buf (c-1)%3 (== stage target (c+2)%3); per-wave vmcnt before the
// barrier proves tile-c data landed; barrier publishes it.
// Read swizzle: 16B slot ^= ((row>>1)&3)<<4; staging pre-applies the inverse
// on the global source (linear gload_lds dest). Bit-exact since R7.
#define FENCE_BARRIER() do { asm volatile("" ::: "memory"); \
    __builtin_amdgcn_s_barrier(); asm volatile("" ::: "memory"); } while (0)
#define WAIT_VM4() asm volatile("s_waitcnt vmcnt(4)" ::: "memory")
#define WAIT_VM0() asm volatile("s_waitcnt vmcnt(0)" ::: "memory")

// stage one K-tile into buffer at byte DB; 4 chunks/wave (A q0,q1; B q0,q1)
#define STAGEALL(DB) do { \
    gload_lds16(spA0, ldsb + (DB) + (wv * 2 + 0) * 1024); \
    gload_lds16(spA1, ldsb + (DB) + (wv * 2 + 1) * 1024); \
    gload_lds16(spB0, ldsb + (DB) + 8192 + (wv * 2 + 0) * 1024); \
    gload_lds16(spB1, ldsb + (DB) + 8192 + (wv * 2 + 1) * 1024); \
    spA0 += 64; spA1 += 64; spB0 += 64; spB1 += 64; } while (0)

#define COMPUTE(CB) do { \
    bf16x8 af[4], bfr[4]; \
    _Pragma("unroll") for (int mi = 0; mi < 4; ++mi) \
        af[mi] = *(const bf16x8*)(ldsb + (CB) + wM * 4096 + mi * 1024 + rowks); \
    _Pragma("unroll") for (int ni = 0; ni < 4; ++ni) \
        bfr[ni] = *(const bf16x8*)(ldsb + (CB) + 8192 + wN * 4096 + ni * 1024 + rowks); \
    _Pragma("unroll") for (int mi = 0; mi < 4; ++mi) \
    _Pragma("unroll") for (int ni = 0; ni < 4; ++ni) \
        acc[mi][ni] = __builtin_amdgcn_mfma_f32_16x16x32_bf16(af[mi], bfr[ni], acc[mi][ni], 0, 0, 0); \
    } while (0)

#define KT(CB, SB) do { \
    WAIT_VM4(); FENCE_BARRIER(); STAGEALL(SB); COMPUTE(CB); } while (0)

__global__ __launch_bounds__(256, 3) void argmax_gemm(const unsigned short* __restrict__ xnb,
                                                      unsigned long long* __restrict__ partial) {
    __shared__ char ldsb[49152];   // 3 x 16KB buffers

    // T1: XCD-bijective swizzle (2080 = 8*260), then triangular decode
    int wg = (int)blockIdx.x;
    int tile = (wg & 7) * (NWG / 8) + (wg >> 3);
    int by = 0, tr = tile;
    while (tr >= NTIL - by) { tr -= NTIL - by; ++by; }
    const int bx = by + tr;  // bx >= by

    const int rowBase = by * 128, colBase = bx * 128;
    const int tid = (int)threadIdx.x;
    const int wv = tid >> 6;   // 0..3
    const int l = tid & 63;
    const int wM = wv >> 1;    // 2 wave-rows x 64
    const int wN = wv & 1;     // 2 wave-cols x 64

    // read-side: lane l reads row (l&15), 16B slot (l>>4); slot ^= ((row>>1)&3)
    const int rowks = (l & 15) * 64 + (((l >> 4) * 16) ^ (((l >> 1) & 3) << 4));

    // stage-side: lane covers chunk-row l>>2, physical slot l&3;
    // source slot = (l&3) ^ ((l>>3)&3)  (inverse of the read swizzle)
    const int scol = (((l & 3) ^ ((l >> 3) & 3)) << 4);
    const char* xb = (const char*)xnb;
    const int r0 = (wv * 2 + 0) * 16 + (l >> 2);
    const int r1 = (wv * 2 + 1) * 16 + (l >> 2);
    const char* spA0 = xb + (size_t)(rowBase + r0) * 2048 + scol;
    const char* spA1 = xb + (size_t)(rowBase + r1) * 2048 + scol;
    const char* spB0 = xb + (size_t)(colBase + r0) * 2048 + scol;
    const char* spB1 = xb + (size_t)(colBase + r1) * 2048 + scol;

    f32x4 acc[4][4];
#pragma unroll
    for (int m = 0; m < 4; ++m)
#pragma unroll
        for (int n = 0; n < 4; ++n) acc[m][n] = f32x4{0.f, 0.f, 0.f, 0.f};

    // prologue: stage tiles 0,1 into buf0,buf1 (8 loads in flight)
    STAGEALL(0);
    STAGEALL(16384);

    // main: tiles 0..29; tile c: compute buf c%3, stage tile c+2 -> buf (c+2)%3
    for (int g = 0; g < 10; ++g) {
        KT(0, 32768);        // c%3==0: compute buf0, stage buf2
        KT(16384, 0);        // c%3==1: compute buf1, stage buf0
        KT(32768, 16384);    // c%3==2: compute buf2, stage buf1
    }
    // tail: tile 30 (buf0, 8 outstanding -> vm4), tile 31 (buf1, vm0)
    WAIT_VM4(); FENCE_BARRIER(); COMPUTE(0);
    WAIT_VM0(); FENCE_BARRIER(); COMPUTE(16384);

    // ---- epilogue: fused argmax. C/D: col = lane&15, row = (lane>>4)*4 + reg ----
    // row path: rows of by-block; slot = (bx-by)*2 + wN  in [0, (64-by)*2)
#pragma unroll
    for (int mi = 0; mi < 4; ++mi) {
#pragma unroll
        for (int r = 0; r < 4; ++r) {
            int gi = rowBase + wM * 64 + mi * 16 + (l >> 4) * 4 + r;
            float mx = -3.0f;
            int mc = 0x7FFFFFFF;
#pragma unroll
            for (int ni = 0; ni < 4; ++ni) {
                int gj = colBase + wN * 64 + ni * 16 + (l & 15);
                float v = (gi == gj) ? -2.0f : acc[mi][ni][r];
                if (v > mx) { mx = v; mc = gj; }
            }
#pragma unroll
            for (int off = 1; off < 16; off <<= 1) {
                float omx = __shfl_xor(mx, off, 64);
                int omc = __shfl_xor(mc, off, 64);
                if (omx > mx || (omx == mx && omc < mc)) { mx = omx; mc = omc; }
            }
            if ((l & 15) == 0)
                partial[(size_t)gi * SLOTS + (bx - by) * 2 + wN] = packmax(mx, mc);
        }
    }
    // col path (transpose view, bx > by): rows of bx-block; slot = (64-bx)*2 + by*2 + wM
    if (bx > by) {
#pragma unroll
        for (int ni = 0; ni < 4; ++ni) {
            int gj = colBase + wN * 64 + ni * 16 + (l & 15);
            float mx = -3.0f;
            int mc = 0x7FFFFFFF;
#pragma unroll
            for (int mi = 0; mi < 4; ++mi) {
#pragma unroll
                for (int r = 0; r < 4; ++r) {
                    int gi = rowBase + wM * 64 + mi * 16 + (l >> 4) * 4 + r;
                    float v = (gi == gj) ? -2.0f : acc[mi][ni][r];
                    if (v > mx) { mx = v; mc = gi; }   // ascending gi, strict >
                }
            }
#pragma unroll
            for (int off = 16; off < 64; off <<= 1) {
                float omx = __shfl_xor(mx, off, 64);
                int omc = __shfl_xor(mc, off, 64);
                if (omx > mx || (omx == mx && omc < mc)) { mx = omx; mc = omc; }
            }
            if ((l >> 4) == 0)
                partial[(size_t)gj * SLOTS + (NTIL - bx) * 2 + by * 2 + wM] = packmax(mx, mc);
        }
    }
}

// ---------- kernel 3: slot-reduce -> NN idx; exact fp32 distance + loss (wave/row) ----------
__global__ __launch_bounds__(256) void dist_k(const float* __restrict__ x,
                                              const unsigned long long* __restrict__ partial,
                                              float* __restrict__ rowloss) {
    int i = blockIdx.x * 4 + (threadIdx.x >> 6);
    int l = threadIdx.x & 63;
    // all 128 slots are written for every row (exact partition)
    unsigned long long p = partial[(size_t)i * SLOTS + l];
    {
        unsigned long long o = partial[(size_t)i * SLOTS + l + 64];
        if (o > p) p = o;
    }
#pragma unroll
    for (int off = 1; off < 64; off <<= 1) {
        unsigned long long o = __shfl_xor(p, off, 64);
        if (o > p) p = o;
    }
    int j = (int)(~(unsigned int)(p & 0xFFFFFFFFull));  // wave-uniform

    const float4* xi = (const float4*)(x + (size_t)i * ND);
    const float4* xj = (const float4*)(x + (size_t)j * ND);
    float4 a[4], b[4];
    float sa = 0.f, sb = 0.f;
#pragma unroll
    for (int q = 0; q < 4; ++q) {
        a[q] = xi[q * 64 + l];
        b[q] = xj[q * 64 + l];
        sa += a[q].x * a[q].x + a[q].y * a[q].y + a[q].z * a[q].z + a[q].w * a[q].w;
        sb += b[q].x * b[q].x + b[q].y * b[q].y + b[q].z * b[q].z + b[q].w * b[q].w;
    }
#pragma unroll
    for (int off = 1; off < 64; off <<= 1) {
        sa += __shfl_xor(sa, off, 64);
        sb += __shfl_xor(sb, off, 64);
    }
    float ia = 1.0f / fmaxf(sqrtf(sa), KEPS);
    float ib = 1.0f / fmaxf(sqrtf(sb), KEPS);
    float ss = 0.f;
#pragma unroll
    for (int q = 0; q < 4; ++q) {
        float dx = a[q].x * ia - b[q].x * ib + KEPS;
        float dy = a[q].y * ia - b[q].y * ib + KEPS;
        float dz = a[q].z * ia - b[q].z * ib + KEPS;
        float dw = a[q].w * ia - b[q].w * ib + KEPS;
        ss += dx * dx + dy * dy + dz * dz + dw * dw;
    }
#pragma unroll
    for (int off = 1; off < 64; off <<= 1) ss += __shfl_xor(ss, off, 64);
    if (l == 0) rowloss[i] = -logf(sqrtf(ss) + KEPS);
}

// ---------- kernel 4: mean over rows ----------
__global__ __launch_bounds__(1024) void reduce_k(const float* __restrict__ rowloss,
                                                 float* __restrict__ out) {
    int t = threadIdx.x;
    float s = 0.0f;
#pragma unroll
    for (int k = 0; k < 8; ++k) s += rowloss[t + k * 1024];
#pragma unroll
    for (int off = 32; off > 0; off >>= 1) s += __shfl_down(s, off, 64);
    __shared__ float sred[16];
    if ((t & 63) == 0) sred[t >> 6] = s;
    __syncthreads();
    if (t == 0) {
        float tot = 0.0f;
        for (int k = 0; k < 16; ++k) tot += sred[k];
        out[0] = tot / (float)NB;
    }
}

// ---------- launch ----------
extern "C" void kernel_launch(void* const* d_in, const int* in_sizes, int n_in,
                              void* d_out, int out_size, void* d_ws, size_t ws_size,
                              hipStream_t stream) {
    const float* x = (const float*)d_in[0];
    float* out = (float*)d_out;

    char* ws = (char*)d_ws;
    unsigned short* xnb = (unsigned short*)ws;                        // 16 MB
    unsigned long long* partial =
        (unsigned long long*)(ws + (size_t)NB * ND * 2);              // 8 MB
    float* rowloss = (float*)(ws + (size_t)NB * ND * 2 + (size_t)NB * SLOTS * 8);  // 32 KB

    normalize_k<<<NB / 4, 256, 0, stream>>>(x, xnb);
    argmax_gemm<<<NWG, 256, 0, stream>>>(xnb, partial);
    dist_k<<<NB / 4, 256, 0, stream>>>(x, partial, rowloss);
    reduce_k<<<1, 1024, 0, stream>>>(rowloss, out);
}